// Round 1
// baseline (3284.547 us; speedup 1.0000x reference)
//
#include <hip/hip_runtime.h>

#define NN_F 500
#define HID 64
#define NC 40

// ---- edge_index may arrive as int32 (harness-converted) or raw int64. ----
__device__ __forceinline__ int load_edge(const void* ei, long long idx, int is64) {
    if (is64) return (int)((const long long*)ei)[idx];
    return ((const int*)ei)[idx];
}

// Detect layout: if data is int64 (little-endian, values < 2^31), every odd
// 32-bit word is zero. Random int32 node ids would essentially never be.
__global__ __launch_bounds__(256) void detect_kernel(const unsigned int* w, int* flag) {
    __shared__ unsigned int red[256];
    unsigned int acc = 0;
    for (int i = threadIdx.x; i < 2048; i += 256) acc |= w[2 * i + 1];
    red[threadIdx.x] = acc;
    __syncthreads();
    for (int s = 128; s > 0; s >>= 1) {
        if (threadIdx.x < s) red[threadIdx.x] |= red[threadIdx.x + s];
        __syncthreads();
    }
    if (threadIdx.x == 0) flag[0] = (red[0] == 0u) ? 1 : 0;
}

__global__ __launch_bounds__(256) void deg_kernel(const void* ei, const int* flag,
                                                  float* deg, int E) {
    int is64 = flag[0];
    long long e = (long long)blockIdx.x * 256 + threadIdx.x;
    if (e < E) {
        int d = load_edge(ei, (long long)E + e, is64);
        atomicAdd(&deg[d], 1.0f);
    }
}

__global__ __launch_bounds__(256) void dinv_kernel(const float* __restrict__ deg,
                                                   float* __restrict__ dinv, int n) {
    int i = blockIdx.x * 256 + threadIdx.x;
    if (i < n) dinv[i] = rsqrtf(deg[i] + 1.0f);  // +1 self-loop; always > 0
}

// Tall-skinny GEMM: out[n x C] = X[n x K] @ W[K x C].
// Wave = 64 lanes = 64 output columns (c), 4 wavegroups x 32 rows per block.
// X indices are wave-uniform (readfirstlane) -> scalar loads; W reads coalesced.
template<int K, int C, int KB>
__global__ __launch_bounds__(256) void gemm_rc(const float* __restrict__ X,
                                               const float* __restrict__ W,
                                               float* __restrict__ out, int n) {
    const int c = threadIdx.x & 63;
    const int rg = threadIdx.x >> 6;
    const int rowBase = __builtin_amdgcn_readfirstlane(blockIdx.x * 128 + rg * 32);
    float acc[32];
#pragma unroll
    for (int r = 0; r < 32; ++r) acc[r] = 0.0f;
    for (int k0 = 0; k0 < K; k0 += KB) {
        float w[KB];
#pragma unroll
        for (int kk = 0; kk < KB; ++kk)
            w[kk] = (c < C) ? W[(k0 + kk) * C + c] : 0.0f;
#pragma unroll
        for (int r = 0; r < 32; ++r) {
            const int row = rowBase + r;
            if (row < n) {
                const float* xr = X + (long long)row * K + k0;
#pragma unroll
                for (int kk = 0; kk < KB; ++kk)
                    acc[r] = fmaf(xr[kk], w[kk], acc[r]);
            }
        }
    }
    if (c < C) {
#pragma unroll
        for (int r = 0; r < 32; ++r) {
            const int row = rowBase + r;
            if (row < n) out[(long long)row * C + c] = acc[r];
        }
    }
}

// agg[i] = dinv[node]^2 * h[i]   (self-loop contribution; also initializes agg)
template<int C>
__global__ __launch_bounds__(256) void self_init(const float* __restrict__ h,
                                                 const float* __restrict__ dinv,
                                                 float* __restrict__ agg, int n) {
    long long i = (long long)blockIdx.x * 256 + threadIdx.x;
    if (i < (long long)n * C) {
        int node = (int)(i / C);
        float dv = dinv[node];
        agg[i] = dv * dv * h[i];
    }
}

// agg[dst] += dinv[src]*dinv[dst] * h[src]; QPE = C/4 threads per edge (float4)
template<int C, int QPE>
__global__ __launch_bounds__(256) void scatter_kernel(const void* ei, const int* flag,
                                                      const float* __restrict__ dinv,
                                                      const float* __restrict__ h,
                                                      float* __restrict__ agg, int E) {
    int is64 = flag[0];
    long long gid = (long long)blockIdx.x * 256 + threadIdx.x;
    int e = (int)(gid / QPE);
    int q = (int)(gid - (long long)e * QPE);
    if (e >= E) return;
    int s = load_edge(ei, e, is64);
    int d = load_edge(ei, (long long)E + e, is64);
    float norm = dinv[s] * dinv[d];
    const float4 hv = *(const float4*)(h + (long long)s * C + q * 4);
    float* ap = agg + (long long)d * C + q * 4;
    atomicAdd(ap + 0, norm * hv.x);
    atomicAdd(ap + 1, norm * hv.y);
    atomicAdd(ap + 2, norm * hv.z);
    atomicAdd(ap + 3, norm * hv.w);
}

template<int C>
__global__ __launch_bounds__(256) void bias_relu(float* __restrict__ agg,
                                                 const float* __restrict__ b, int n) {
    long long i = (long long)blockIdx.x * 256 + threadIdx.x;
    if (i < (long long)n * C) {
        int c = (int)(i % C);
        float v = agg[i] + b[c];
        agg[i] = v > 0.f ? v : 0.f;
    }
}

// out = log_softmax(relu(agg + b2)) per node over NC classes
__global__ __launch_bounds__(256) void final_kernel(const float* __restrict__ agg,
                                                    const float* __restrict__ b2,
                                                    float* __restrict__ out, int n) {
    int node = blockIdx.x * 256 + threadIdx.x;
    if (node >= n) return;
    float v[NC];
    float m = -1e30f;
#pragma unroll
    for (int c = 0; c < NC; ++c) {
        float t = agg[(long long)node * NC + c] + b2[c];
        t = t > 0.f ? t : 0.f;
        v[c] = t;
        m = fmaxf(m, t);
    }
    float ssum = 0.f;
#pragma unroll
    for (int c = 0; c < NC; ++c) ssum += expf(v[c] - m);
    float ls = logf(ssum);
#pragma unroll
    for (int c = 0; c < NC; ++c) out[(long long)node * NC + c] = v[c] - m - ls;
}

extern "C" void kernel_launch(void* const* d_in, const int* in_sizes, int n_in,
                              void* d_out, int out_size, void* d_ws, size_t ws_size,
                              hipStream_t stream) {
    const float* x  = (const float*)d_in[0];
    const void*  ei = d_in[1];
    const float* W1 = (const float*)d_in[2];
    const float* b1 = (const float*)d_in[3];
    const float* W2 = (const float*)d_in[4];
    const float* b2 = (const float*)d_in[5];
    float* out = (float*)d_out;
    const int n = in_sizes[0] / NN_F;   // 100000
    const int E = in_sizes[1] / 2;      // 1600000

    float* base = (float*)d_ws;
    int*   flag = (int*)d_ws;               // [0..15] reserved
    float* deg  = base + 64;                // n
    float* dinv = deg + n;                  // n
    float* h1   = dinv + n;                 // n*64
    float* agg1 = h1 + (long long)n * HID;  // n*64
    float* h2   = agg1 + (long long)n * HID;// n*40
    float* agg2 = h2 + (long long)n * NC;   // n*40   total ~84 MB

    hipMemsetAsync(deg, 0, (size_t)n * sizeof(float), stream);
    detect_kernel<<<1, 256, 0, stream>>>((const unsigned int*)ei, flag);
    deg_kernel<<<(E + 255) / 256, 256, 0, stream>>>(ei, flag, deg, E);
    dinv_kernel<<<(n + 255) / 256, 256, 0, stream>>>(deg, dinv, n);

    gemm_rc<NN_F, HID, 20><<<(n + 127) / 128, 256, 0, stream>>>(x, W1, h1, n);
    self_init<HID><<<(int)(((long long)n * HID + 255) / 256), 256, 0, stream>>>(h1, dinv, agg1, n);
    scatter_kernel<HID, 16><<<(int)(((long long)E * 16 + 255) / 256), 256, 0, stream>>>(ei, flag, dinv, h1, agg1, E);
    bias_relu<HID><<<(int)(((long long)n * HID + 255) / 256), 256, 0, stream>>>(agg1, b1, n);

    gemm_rc<HID, NC, 16><<<(n + 127) / 128, 256, 0, stream>>>(agg1, W2, h2, n);
    self_init<NC><<<(int)(((long long)n * NC + 255) / 256), 256, 0, stream>>>(h2, dinv, agg2, n);
    scatter_kernel<NC, 10><<<(int)(((long long)E * 10 + 255) / 256), 256, 0, stream>>>(ei, flag, dinv, h2, agg2, E);

    final_kernel<<<(n + 255) / 256, 256, 0, stream>>>(agg2, b2, out, n);
}

// Round 2
// 1192.922 us; speedup vs baseline: 2.7534x; 2.7534x over previous
//
#include <hip/hip_runtime.h>

#define NN_F 500
#define HID 64
#define NC 40
#define SCAN_T 256
#define SCAN_E 8
#define SCAN_B (SCAN_T * SCAN_E)  // 2048 elements per scan block

// ---- edge_index may arrive as int32 (harness-converted) or raw int64. ----
__device__ __forceinline__ int load_edge(const void* ei, long long idx, int is64) {
    if (is64) return (int)((const long long*)ei)[idx];
    return ((const int*)ei)[idx];
}

// Detect layout: int64 little-endian with values < 2^31 -> odd 32-bit words all 0.
__global__ __launch_bounds__(256) void detect_kernel(const unsigned int* w, int* flag) {
    __shared__ unsigned int red[256];
    unsigned int acc = 0;
    for (int i = threadIdx.x; i < 2048; i += 256) acc |= w[2 * i + 1];
    red[threadIdx.x] = acc;
    __syncthreads();
    for (int s = 128; s > 0; s >>= 1) {
        if (threadIdx.x < s) red[threadIdx.x] |= red[threadIdx.x + s];
        __syncthreads();
    }
    if (threadIdx.x == 0) flag[0] = (red[0] == 0u) ? 1 : 0;
}

__global__ __launch_bounds__(256) void deg_kernel(const void* ei, const int* flag,
                                                  int* deg, int E) {
    int is64 = flag[0];
    long long e = (long long)blockIdx.x * 256 + threadIdx.x;
    if (e < E) {
        int d = load_edge(ei, (long long)E + e, is64);
        atomicAdd(&deg[d], 1);
    }
}

__global__ __launch_bounds__(256) void dinv_kernel(const int* __restrict__ deg,
                                                   float* __restrict__ dinv, int n) {
    int i = blockIdx.x * 256 + threadIdx.x;
    if (i < n) dinv[i] = rsqrtf((float)deg[i] + 1.0f);  // +1 self-loop; always > 0
}

// ---- 3-phase exclusive scan of deg -> off ----
__global__ __launch_bounds__(SCAN_T) void scan1(const int* __restrict__ deg,
                                                int* __restrict__ off,
                                                int* __restrict__ bsums, int n) {
    __shared__ int lds[SCAN_T];
    int base = blockIdx.x * SCAN_B + threadIdx.x * SCAN_E;
    int v[SCAN_E];
    int local = 0;
#pragma unroll
    for (int k = 0; k < SCAN_E; ++k) {
        v[k] = (base + k < n) ? deg[base + k] : 0;
        local += v[k];
    }
    lds[threadIdx.x] = local;
    __syncthreads();
    for (int o = 1; o < SCAN_T; o <<= 1) {
        int t = (threadIdx.x >= o) ? lds[threadIdx.x - o] : 0;
        __syncthreads();
        lds[threadIdx.x] += t;
        __syncthreads();
    }
    int prefix = lds[threadIdx.x] - local;  // exclusive for this thread
    if (threadIdx.x == SCAN_T - 1) bsums[blockIdx.x] = lds[threadIdx.x];
    int run = prefix;
#pragma unroll
    for (int k = 0; k < SCAN_E; ++k) {
        if (base + k < n) { off[base + k] = run; run += v[k]; }
    }
}

__global__ void scan2(int* bsums, int* off, int nb, int n) {
    if (threadIdx.x == 0 && blockIdx.x == 0) {
        int run = 0;
        for (int i = 0; i < nb; ++i) { int t = bsums[i]; bsums[i] = run; run += t; }
        off[n] = run;  // == E
    }
}

__global__ __launch_bounds__(SCAN_T) void scan3(int* __restrict__ off,
                                                int* __restrict__ cur,
                                                const int* __restrict__ bsums, int n) {
    int base = blockIdx.x * SCAN_B + threadIdx.x * SCAN_E;
    int add = bsums[blockIdx.x];
#pragma unroll
    for (int k = 0; k < SCAN_E; ++k) {
        int i = base + k;
        if (i < n) { int v = off[i] + add; off[i] = v; cur[i] = v; }
    }
}

// Scatter edges into CSR buckets by dst. Stores src id and norm weight.
__global__ __launch_bounds__(256) void build_kernel(const void* ei, const int* flag,
                                                    const float* __restrict__ dinv,
                                                    int* __restrict__ cur,
                                                    int* __restrict__ csr_src,
                                                    float* __restrict__ csr_w, int E) {
    int is64 = flag[0];
    long long e = (long long)blockIdx.x * 256 + threadIdx.x;
    if (e >= E) return;
    int s = load_edge(ei, e, is64);
    int d = load_edge(ei, (long long)E + e, is64);
    int pos = atomicAdd(&cur[d], 1);
    csr_src[pos] = s;
    csr_w[pos] = dinv[s] * dinv[d];
}

// Layer-1 gather: wave per node, lane = feature (C=64). Fuses self-loop, bias, relu.
__global__ __launch_bounds__(256) void gather_l1(const int* __restrict__ csr_src,
                                                 const float* __restrict__ csr_w,
                                                 const int* __restrict__ off,
                                                 const float* __restrict__ h,
                                                 const float* __restrict__ dinv,
                                                 const float* __restrict__ b,
                                                 float* __restrict__ agg, int n) {
    const int lane = threadIdx.x & 63;
    const int node = blockIdx.x * 4 + (threadIdx.x >> 6);
    if (node >= n) return;
    int start = off[node], end = off[node + 1];
    float dv = dinv[node];
    float acc = dv * dv * h[(long long)node * HID + lane];
    while (start < end) {
        int cnt = end - start;
        if (cnt > 64) cnt = 64;
        int sreg = 0; float wreg = 0.f;
        if (lane < cnt) { sreg = csr_src[start + lane]; wreg = csr_w[start + lane]; }
        for (int j = 0; j < cnt; ++j) {
            int s = __shfl(sreg, j);
            float wg = __shfl(wreg, j);
            acc = fmaf(wg, h[(long long)s * HID + lane], acc);
        }
        start += cnt;
    }
    float v = acc + b[lane];
    agg[(long long)node * HID + lane] = v > 0.f ? v : 0.f;
}

// Layer-2 gather fused with bias, relu, log_softmax. Lane = class (40 of 64 active).
__global__ __launch_bounds__(256) void gather_l2(const int* __restrict__ csr_src,
                                                 const float* __restrict__ csr_w,
                                                 const int* __restrict__ off,
                                                 const float* __restrict__ h,
                                                 const float* __restrict__ dinv,
                                                 const float* __restrict__ b,
                                                 float* __restrict__ out, int n) {
    const int lane = threadIdx.x & 63;
    const int node = blockIdx.x * 4 + (threadIdx.x >> 6);
    if (node >= n) return;
    int start = off[node], end = off[node + 1];
    float dv = dinv[node];
    float acc = 0.f;
    if (lane < NC) acc = dv * dv * h[(long long)node * NC + lane];
    while (start < end) {
        int cnt = end - start;
        if (cnt > 64) cnt = 64;
        int sreg = 0; float wreg = 0.f;
        if (lane < cnt) { sreg = csr_src[start + lane]; wreg = csr_w[start + lane]; }
        for (int j = 0; j < cnt; ++j) {
            int s = __shfl(sreg, j);
            float wg = __shfl(wreg, j);
            if (lane < NC) acc = fmaf(wg, h[(long long)s * NC + lane], acc);
        }
        start += cnt;
    }
    float t;
    if (lane < NC) {
        t = acc + b[lane];
        t = t > 0.f ? t : 0.f;
    } else {
        t = -1e30f;
    }
    float m = t;
#pragma unroll
    for (int o = 32; o > 0; o >>= 1) m = fmaxf(m, __shfl_xor(m, o));
    float ex = (lane < NC) ? expf(t - m) : 0.f;
    float ssum = ex;
#pragma unroll
    for (int o = 32; o > 0; o >>= 1) ssum += __shfl_xor(ssum, o);
    if (lane < NC) out[(long long)node * NC + lane] = t - m - logf(ssum);
}

// Tall-skinny GEMM: out[n x C] = X[n x K] @ W[K x C].
template<int K, int C, int KB>
__global__ __launch_bounds__(256) void gemm_rc(const float* __restrict__ X,
                                               const float* __restrict__ W,
                                               float* __restrict__ out, int n) {
    const int c = threadIdx.x & 63;
    const int rg = threadIdx.x >> 6;
    const int rowBase = __builtin_amdgcn_readfirstlane(blockIdx.x * 128 + rg * 32);
    float acc[32];
#pragma unroll
    for (int r = 0; r < 32; ++r) acc[r] = 0.0f;
    for (int k0 = 0; k0 < K; k0 += KB) {
        float w[KB];
#pragma unroll
        for (int kk = 0; kk < KB; ++kk)
            w[kk] = (c < C) ? W[(k0 + kk) * C + c] : 0.0f;
#pragma unroll
        for (int r = 0; r < 32; ++r) {
            const int row = rowBase + r;
            if (row < n) {
                const float* xr = X + (long long)row * K + k0;
#pragma unroll
                for (int kk = 0; kk < KB; ++kk)
                    acc[r] = fmaf(xr[kk], w[kk], acc[r]);
            }
        }
    }
    if (c < C) {
#pragma unroll
        for (int r = 0; r < 32; ++r) {
            const int row = rowBase + r;
            if (row < n) out[(long long)row * C + c] = acc[r];
        }
    }
}

static inline char* align256(char* p) {
    return (char*)(((uintptr_t)p + 255) & ~(uintptr_t)255);
}

extern "C" void kernel_launch(void* const* d_in, const int* in_sizes, int n_in,
                              void* d_out, int out_size, void* d_ws, size_t ws_size,
                              hipStream_t stream) {
    const float* x  = (const float*)d_in[0];
    const void*  ei = d_in[1];
    const float* W1 = (const float*)d_in[2];
    const float* b1 = (const float*)d_in[3];
    const float* W2 = (const float*)d_in[4];
    const float* b2 = (const float*)d_in[5];
    float* out = (float*)d_out;
    const int n = in_sizes[0] / NN_F;   // 100000
    const int E = in_sizes[1] / 2;      // 1600000
    const int nScanBlocks = (n + SCAN_B - 1) / SCAN_B;  // 49

    char* p = (char*)d_ws;
    int* flag = (int*)p;                 p = align256(p + 16 * sizeof(int));
    int* deg  = (int*)p;                 p = align256(p + (size_t)n * sizeof(int));
    int* off  = (int*)p;                 p = align256(p + (size_t)(n + 1) * sizeof(int));
    int* cur  = (int*)p;                 p = align256(p + (size_t)n * sizeof(int));
    int* bsums = (int*)p;                p = align256(p + 256 * sizeof(int));
    float* dinv = (float*)p;             p = align256(p + (size_t)n * sizeof(float));
    int* csr_src = (int*)p;              p = align256(p + (size_t)E * sizeof(int));
    float* csr_w = (float*)p;            p = align256(p + (size_t)E * sizeof(float));
    float* h1   = (float*)p;             p = align256(p + (size_t)n * HID * sizeof(float));
    float* agg1 = (float*)p;             p = align256(p + (size_t)n * HID * sizeof(float));
    float* h2   = (float*)p;             p = align256(p + (size_t)n * NC * sizeof(float));

    hipMemsetAsync(deg, 0, (size_t)n * sizeof(int), stream);
    detect_kernel<<<1, 256, 0, stream>>>((const unsigned int*)ei, flag);
    deg_kernel<<<(E + 255) / 256, 256, 0, stream>>>(ei, flag, deg, E);
    dinv_kernel<<<(n + 255) / 256, 256, 0, stream>>>(deg, dinv, n);

    scan1<<<nScanBlocks, SCAN_T, 0, stream>>>(deg, off, bsums, n);
    scan2<<<1, 64, 0, stream>>>(bsums, off, nScanBlocks, n);
    scan3<<<nScanBlocks, SCAN_T, 0, stream>>>(off, cur, bsums, n);
    build_kernel<<<(E + 255) / 256, 256, 0, stream>>>(ei, flag, dinv, cur, csr_src, csr_w, E);

    gemm_rc<NN_F, HID, 20><<<(n + 127) / 128, 256, 0, stream>>>(x, W1, h1, n);
    gather_l1<<<(n + 3) / 4, 256, 0, stream>>>(csr_src, csr_w, off, h1, dinv, b1, agg1, n);

    gemm_rc<HID, NC, 16><<<(n + 127) / 128, 256, 0, stream>>>(agg1, W2, h2, n);
    gather_l2<<<(n + 3) / 4, 256, 0, stream>>>(csr_src, csr_w, off, h2, dinv, b2, out, n);
}

// Round 4
// 732.346 us; speedup vs baseline: 4.4850x; 1.6289x over previous
//
#include <hip/hip_runtime.h>

#define NN_F 500
#define HID 64
#define NC 40
#define SCAN_T 256
#define SCAN_E 8
#define SCAN_B (SCAN_T * SCAN_E)

typedef short s8v __attribute__((ext_vector_type(8)));
typedef short s4v __attribute__((ext_vector_type(4)));
typedef float f4v __attribute__((ext_vector_type(4)));

struct HL { short h, l; };
__device__ __forceinline__ HL split_bf16(float x) {
    HL r;
    unsigned u = __float_as_uint(x);
    r.h = (short)(u >> 16);
    float hf = __uint_as_float(u & 0xffff0000u);
    r.l = (short)(__float_as_uint(x - hf) >> 16);
    return r;
}

// ---- edge_index may arrive as int32 (harness-converted) or raw int64. ----
__device__ __forceinline__ int load_edge(const void* ei, long long idx, int is64) {
    if (is64) return (int)((const long long*)ei)[idx];
    return ((const int*)ei)[idx];
}

__global__ __launch_bounds__(256) void detect_kernel(const unsigned int* w, int* flag) {
    __shared__ unsigned int red[256];
    unsigned int acc = 0;
    for (int i = threadIdx.x; i < 2048; i += 256) acc |= w[2 * i + 1];
    red[threadIdx.x] = acc;
    __syncthreads();
    for (int s = 128; s > 0; s >>= 1) {
        if (threadIdx.x < s) red[threadIdx.x] |= red[threadIdx.x + s];
        __syncthreads();
    }
    if (threadIdx.x == 0) flag[0] = (red[0] == 0u) ? 1 : 0;
}

__global__ __launch_bounds__(256) void deg_kernel(const void* ei, const int* flag,
                                                  int* deg, int E) {
    int is64 = flag[0];
    long long e = (long long)blockIdx.x * 256 + threadIdx.x;
    if (e < E) {
        int d = load_edge(ei, (long long)E + e, is64);
        atomicAdd(&deg[d], 1);
    }
}

__global__ __launch_bounds__(256) void dinv_kernel(const int* __restrict__ deg,
                                                   float* __restrict__ dinv, int n) {
    int i = blockIdx.x * 256 + threadIdx.x;
    if (i < n) dinv[i] = rsqrtf((float)deg[i] + 1.0f);
}

// ---- 3-phase exclusive scan of deg -> off ----
__global__ __launch_bounds__(SCAN_T) void scan1(const int* __restrict__ deg,
                                                int* __restrict__ off,
                                                int* __restrict__ bsums, int n) {
    __shared__ int lds[SCAN_T];
    int base = blockIdx.x * SCAN_B + threadIdx.x * SCAN_E;
    int v[SCAN_E];
    int local = 0;
#pragma unroll
    for (int k = 0; k < SCAN_E; ++k) {
        v[k] = (base + k < n) ? deg[base + k] : 0;
        local += v[k];
    }
    lds[threadIdx.x] = local;
    __syncthreads();
    for (int o = 1; o < SCAN_T; o <<= 1) {
        int t = (threadIdx.x >= o) ? lds[threadIdx.x - o] : 0;
        __syncthreads();
        lds[threadIdx.x] += t;
        __syncthreads();
    }
    int prefix = lds[threadIdx.x] - local;
    if (threadIdx.x == SCAN_T - 1) bsums[blockIdx.x] = lds[threadIdx.x];
    int run = prefix;
#pragma unroll
    for (int k = 0; k < SCAN_E; ++k) {
        if (base + k < n) { off[base + k] = run; run += v[k]; }
    }
}

__global__ void scan2(int* bsums, int* off, int nb, int n) {
    if (threadIdx.x == 0 && blockIdx.x == 0) {
        int run = 0;
        for (int i = 0; i < nb; ++i) { int t = bsums[i]; bsums[i] = run; run += t; }
        off[n] = run;
    }
}

__global__ __launch_bounds__(SCAN_T) void scan3(int* __restrict__ off,
                                                int* __restrict__ cur,
                                                const int* __restrict__ bsums, int n) {
    int base = blockIdx.x * SCAN_B + threadIdx.x * SCAN_E;
    int add = bsums[blockIdx.x];
#pragma unroll
    for (int k = 0; k < SCAN_E; ++k) {
        int i = base + k;
        if (i < n) { int v = off[i] + add; off[i] = v; cur[i] = v; }
    }
}

__global__ __launch_bounds__(256) void build_kernel(const void* ei, const int* flag,
                                                    const float* __restrict__ dinv,
                                                    int* __restrict__ cur,
                                                    int* __restrict__ csr_src,
                                                    float* __restrict__ csr_w, int E) {
    int is64 = flag[0];
    long long e = (long long)blockIdx.x * 256 + threadIdx.x;
    if (e >= E) return;
    int s = load_edge(ei, e, is64);
    int d = load_edge(ei, (long long)E + e, is64);
    int pos = atomicAdd(&cur[d], 1);
    csr_src[pos] = s;
    csr_w[pos] = dinv[s] * dinv[d];
}

// ---- W prep: fp32 [K][Nc] -> transposed split-bf16 [N][KP], zero-padded ----
__global__ __launch_bounds__(256) void wprep(const float* __restrict__ W,
                                             short* __restrict__ Wh, short* __restrict__ Wl,
                                             int K, int KP, int Nc, int N) {
    int id = blockIdx.x * 256 + threadIdx.x;
    if (id >= N * KP) return;
    int nn = id / KP, k = id % KP;
    float v = (k < K && nn < Nc) ? W[(long long)k * Nc + nn] : 0.f;
    HL r = split_bf16(v);
    Wh[nn * KP + k] = r.h;
    Wl[nn * KP + k] = r.l;
}

// ---- MFMA GEMM: out[n x 64] = A[n x K] @ Wt^T, split-bf16 3-term ----
// Block tile: 128 rows x 64 cols, K-tile 32. 4 waves, each 32 rows x 64 cols.
template<int KPAD>
__global__ __launch_bounds__(256) void gemm_mfma(const float* __restrict__ A,
                                                 const short* __restrict__ Wh,
                                                 const short* __restrict__ Wl,
                                                 float* __restrict__ out,
                                                 int n, int K) {
    __shared__ short Xh[128 * 32], Xl[128 * 32];
    __shared__ short Bh[64 * 32], Bl[64 * 32];
    const int t = threadIdx.x;
    const int row0 = blockIdx.x * 128;
    const int wid = t >> 6, lane = t & 63, q = lane >> 4, nn = lane & 15;

    f4v acc[2][4];
#pragma unroll
    for (int mt = 0; mt < 2; ++mt)
#pragma unroll
        for (int ct = 0; ct < 4; ++ct) acc[mt][ct] = (f4v){0.f, 0.f, 0.f, 0.f};

    for (int k0 = 0; k0 < KPAD; k0 += 32) {
        // stage B tile (straight copy, pre-transposed/split in global)
        {
            int bn = t >> 2, kq = t & 3;
            *(s8v*)&Bh[bn * 32 + kq * 8] = *(const s8v*)&Wh[bn * KPAD + k0 + kq * 8];
            *(s8v*)&Bl[bn * 32 + kq * 8] = *(const s8v*)&Wl[bn * KPAD + k0 + kq * 8];
        }
        // stage A tile with on-the-fly fp32 -> (hi,lo) bf16 split
        {
            int kq = t & 7, rbase = t >> 3;
#pragma unroll
            for (int rr = 0; rr < 4; ++rr) {
                int row = rr * 32 + rbase;
                int grow = row0 + row;
                int k = k0 + kq * 4;
                float v0 = 0.f, v1 = 0.f, v2 = 0.f, v3 = 0.f;
                if (grow < n) {
                    if (k + 4 <= K) {
                        float4 v = *(const float4*)&A[(long long)grow * K + k];
                        v0 = v.x; v1 = v.y; v2 = v.z; v3 = v.w;
                    } else {
                        if (k + 0 < K) v0 = A[(long long)grow * K + k + 0];
                        if (k + 1 < K) v1 = A[(long long)grow * K + k + 1];
                        if (k + 2 < K) v2 = A[(long long)grow * K + k + 2];
                        if (k + 3 < K) v3 = A[(long long)grow * K + k + 3];
                    }
                }
                HL r0 = split_bf16(v0), r1 = split_bf16(v1);
                HL r2 = split_bf16(v2), r3 = split_bf16(v3);
                s4v h4, l4;
                h4[0] = r0.h; l4[0] = r0.l;
                h4[1] = r1.h; l4[1] = r1.l;
                h4[2] = r2.h; l4[2] = r2.l;
                h4[3] = r3.h; l4[3] = r3.l;
                *(s4v*)&Xh[row * 32 + kq * 4] = h4;
                *(s4v*)&Xl[row * 32 + kq * 4] = l4;
            }
        }
        __syncthreads();

        const s8v ah0 = *(const s8v*)&Xh[(wid * 32 + nn) * 32 + q * 8];
        const s8v ah1 = *(const s8v*)&Xh[(wid * 32 + 16 + nn) * 32 + q * 8];
        const s8v al0 = *(const s8v*)&Xl[(wid * 32 + nn) * 32 + q * 8];
        const s8v al1 = *(const s8v*)&Xl[(wid * 32 + 16 + nn) * 32 + q * 8];
#pragma unroll
        for (int ct = 0; ct < 4; ++ct) {
            const s8v bh = *(const s8v*)&Bh[(ct * 16 + nn) * 32 + q * 8];
            const s8v bl = *(const s8v*)&Bl[(ct * 16 + nn) * 32 + q * 8];
            acc[0][ct] = __builtin_amdgcn_mfma_f32_16x16x32_bf16(ah0, bh, acc[0][ct], 0, 0, 0);
            acc[0][ct] = __builtin_amdgcn_mfma_f32_16x16x32_bf16(ah0, bl, acc[0][ct], 0, 0, 0);
            acc[0][ct] = __builtin_amdgcn_mfma_f32_16x16x32_bf16(al0, bh, acc[0][ct], 0, 0, 0);
            acc[1][ct] = __builtin_amdgcn_mfma_f32_16x16x32_bf16(ah1, bh, acc[1][ct], 0, 0, 0);
            acc[1][ct] = __builtin_amdgcn_mfma_f32_16x16x32_bf16(ah1, bl, acc[1][ct], 0, 0, 0);
            acc[1][ct] = __builtin_amdgcn_mfma_f32_16x16x32_bf16(al1, bh, acc[1][ct], 0, 0, 0);
        }
        __syncthreads();
    }

    // epilogue: C/D layout col=lane&15, row=(lane>>4)*4+r  [m89-verified]
#pragma unroll
    for (int mt = 0; mt < 2; ++mt)
#pragma unroll
        for (int ct = 0; ct < 4; ++ct)
#pragma unroll
            for (int r = 0; r < 4; ++r) {
                int row = row0 + wid * 32 + mt * 16 + q * 4 + r;
                if (row < n) out[(long long)row * 64 + ct * 16 + nn] = acc[mt][ct][r];
            }
}

// Layer-1 gather: wave per node, lane = feature (64). Fuses self-loop, bias, relu.
__global__ __launch_bounds__(256) void gather_l1(const int* __restrict__ csr_src,
                                                 const float* __restrict__ csr_w,
                                                 const int* __restrict__ off,
                                                 const float* __restrict__ h,
                                                 const float* __restrict__ dinv,
                                                 const float* __restrict__ b,
                                                 float* __restrict__ agg, int n) {
    const int lane = threadIdx.x & 63;
    const int node = blockIdx.x * 4 + (threadIdx.x >> 6);
    if (node >= n) return;
    int start = off[node], end = off[node + 1];
    float dv = dinv[node];
    float acc = dv * dv * h[(long long)node * HID + lane];
    while (start < end) {
        int cnt = end - start;
        if (cnt > 64) cnt = 64;
        int sreg = 0; float wreg = 0.f;
        if (lane < cnt) { sreg = csr_src[start + lane]; wreg = csr_w[start + lane]; }
        for (int j = 0; j < cnt; ++j) {
            int s = __shfl(sreg, j);
            float wg = __shfl(wreg, j);
            acc = fmaf(wg, h[(long long)s * HID + lane], acc);
        }
        start += cnt;
    }
    float v = acc + b[lane];
    agg[(long long)node * HID + lane] = v > 0.f ? v : 0.f;
}

// Layer-2 gather fused with bias, relu, log_softmax. h has stride 64, cols 0..39 valid.
__global__ __launch_bounds__(256) void gather_l2(const int* __restrict__ csr_src,
                                                 const float* __restrict__ csr_w,
                                                 const int* __restrict__ off,
                                                 const float* __restrict__ h,
                                                 const float* __restrict__ dinv,
                                                 const float* __restrict__ b,
                                                 float* __restrict__ out, int n) {
    const int lane = threadIdx.x & 63;
    const int node = blockIdx.x * 4 + (threadIdx.x >> 6);
    if (node >= n) return;
    int start = off[node], end = off[node + 1];
    float dv = dinv[node];
    float acc = 0.f;
    if (lane < NC) acc = dv * dv * h[(long long)node * 64 + lane];
    while (start < end) {
        int cnt = end - start;
        if (cnt > 64) cnt = 64;
        int sreg = 0; float wreg = 0.f;
        if (lane < cnt) { sreg = csr_src[start + lane]; wreg = csr_w[start + lane]; }
        for (int j = 0; j < cnt; ++j) {
            int s = __shfl(sreg, j);
            float wg = __shfl(wreg, j);
            if (lane < NC) acc = fmaf(wg, h[(long long)s * 64 + lane], acc);
        }
        start += cnt;
    }
    float tv;
    if (lane < NC) {
        tv = acc + b[lane];
        tv = tv > 0.f ? tv : 0.f;
    } else {
        tv = -1e30f;
    }
    float m = tv;
#pragma unroll
    for (int o = 32; o > 0; o >>= 1) m = fmaxf(m, __shfl_xor(m, o));
    float ex = (lane < NC) ? expf(tv - m) : 0.f;
    float ssum = ex;
#pragma unroll
    for (int o = 32; o > 0; o >>= 1) ssum += __shfl_xor(ssum, o);
    if (lane < NC) out[(long long)node * NC + lane] = tv - m - logf(ssum);
}

static inline char* align256(char* p) {
    return (char*)(((uintptr_t)p + 255) & ~(uintptr_t)255);
}

extern "C" void kernel_launch(void* const* d_in, const int* in_sizes, int n_in,
                              void* d_out, int out_size, void* d_ws, size_t ws_size,
                              hipStream_t stream) {
    const float* x  = (const float*)d_in[0];
    const void*  ei = d_in[1];
    const float* W1 = (const float*)d_in[2];
    const float* b1 = (const float*)d_in[3];
    const float* W2 = (const float*)d_in[4];
    const float* b2 = (const float*)d_in[5];
    float* out = (float*)d_out;
    const int n = in_sizes[0] / NN_F;   // 100000
    const int E = in_sizes[1] / 2;      // 1600000
    const int nScanBlocks = (n + SCAN_B - 1) / SCAN_B;

    char* p = (char*)d_ws;
    int* flag = (int*)p;                 p = align256(p + 16 * sizeof(int));
    int* deg  = (int*)p;                 p = align256(p + (size_t)n * sizeof(int));
    int* off  = (int*)p;                 p = align256(p + (size_t)(n + 1) * sizeof(int));
    int* cur  = (int*)p;                 p = align256(p + (size_t)n * sizeof(int));
    int* bsums = (int*)p;                p = align256(p + 256 * sizeof(int));
    float* dinv = (float*)p;             p = align256(p + (size_t)n * sizeof(float));
    int* csr_src = (int*)p;              p = align256(p + (size_t)E * sizeof(int));
    float* csr_w = (float*)p;            p = align256(p + (size_t)E * sizeof(float));
    short* Wt1h = (short*)p;             p = align256(p + (size_t)64 * 512 * sizeof(short));
    short* Wt1l = (short*)p;             p = align256(p + (size_t)64 * 512 * sizeof(short));
    short* Wt2h = (short*)p;             p = align256(p + (size_t)64 * 64 * sizeof(short));
    short* Wt2l = (short*)p;             p = align256(p + (size_t)64 * 64 * sizeof(short));
    float* h1   = (float*)p;             p = align256(p + (size_t)n * 64 * sizeof(float));
    float* agg1 = (float*)p;             p = align256(p + (size_t)n * 64 * sizeof(float));
    float* h2   = h1;  // reuse: h1 dead after gather_l1

    (void)hipMemsetAsync(deg, 0, (size_t)n * sizeof(int), stream);
    detect_kernel<<<1, 256, 0, stream>>>((const unsigned int*)ei, flag);
    deg_kernel<<<(E + 255) / 256, 256, 0, stream>>>(ei, flag, deg, E);
    dinv_kernel<<<(n + 255) / 256, 256, 0, stream>>>(deg, dinv, n);

    scan1<<<nScanBlocks, SCAN_T, 0, stream>>>(deg, off, bsums, n);
    scan2<<<1, 64, 0, stream>>>(bsums, off, nScanBlocks, n);
    scan3<<<nScanBlocks, SCAN_T, 0, stream>>>(off, cur, bsums, n);
    build_kernel<<<(E + 255) / 256, 256, 0, stream>>>(ei, flag, dinv, cur, csr_src, csr_w, E);

    wprep<<<(64 * 512 + 255) / 256, 256, 0, stream>>>(W1, Wt1h, Wt1l, NN_F, 512, HID, 64);
    wprep<<<(64 * 64 + 255) / 256, 256, 0, stream>>>(W2, Wt2h, Wt2l, HID, 64, NC, 64);

    const int gBlocks = (n + 127) / 128;
    gemm_mfma<512><<<gBlocks, 256, 0, stream>>>(x, Wt1h, Wt1l, h1, n, NN_F);
    gather_l1<<<(n + 3) / 4, 256, 0, stream>>>(csr_src, csr_w, off, h1, dinv, b1, agg1, n);

    gemm_mfma<64><<<gBlocks, 256, 0, stream>>>(agg1, Wt2h, Wt2l, h2, n, HID);
    gather_l2<<<(n + 3) / 4, 256, 0, stream>>>(csr_src, csr_w, off, h2, dinv, b2, out, n);
}

// Round 5
// 607.622 us; speedup vs baseline: 5.4056x; 1.2053x over previous
//
#include <hip/hip_runtime.h>

#define NN_F 500
#define HID 64
#define NC 40
#define SCAN_T 256
#define SCAN_E 8
#define SCAN_B (SCAN_T * SCAN_E)

typedef short s8v __attribute__((ext_vector_type(8)));
typedef short s4v __attribute__((ext_vector_type(4)));
typedef float f4v __attribute__((ext_vector_type(4)));

struct HL { short h, l; };
__device__ __forceinline__ HL split_bf16(float x) {
    HL r;
    unsigned u = __float_as_uint(x);
    r.h = (short)(u >> 16);
    float hf = __uint_as_float(u & 0xffff0000u);
    r.l = (short)(__float_as_uint(x - hf) >> 16);
    return r;
}

__device__ __forceinline__ unsigned short rne_bf16(float x) {
    unsigned u = __float_as_uint(x);
    return (unsigned short)((u + 0x7fffu + ((u >> 16) & 1u)) >> 16);
}
__device__ __forceinline__ float bf16f(unsigned short v) {
    return __uint_as_float((unsigned)v << 16);
}

// ---- edge_index may arrive as int32 (harness-converted) or raw int64. ----
__device__ __forceinline__ int load_edge(const void* ei, long long idx, int is64) {
    if (is64) return (int)((const long long*)ei)[idx];
    return ((const int*)ei)[idx];
}

__global__ __launch_bounds__(256) void detect_kernel(const unsigned int* w, int* flag) {
    __shared__ unsigned int red[256];
    unsigned int acc = 0;
    for (int i = threadIdx.x; i < 2048; i += 256) acc |= w[2 * i + 1];
    red[threadIdx.x] = acc;
    __syncthreads();
    for (int s = 128; s > 0; s >>= 1) {
        if (threadIdx.x < s) red[threadIdx.x] |= red[threadIdx.x + s];
        __syncthreads();
    }
    if (threadIdx.x == 0) flag[0] = (red[0] == 0u) ? 1 : 0;
}

__global__ __launch_bounds__(256) void deg_kernel(const void* ei, const int* flag,
                                                  int* deg, int E) {
    int is64 = flag[0];
    long long e = (long long)blockIdx.x * 256 + threadIdx.x;
    if (e < E) {
        int d = load_edge(ei, (long long)E + e, is64);
        atomicAdd(&deg[d], 1);
    }
}

__global__ __launch_bounds__(256) void dinv_kernel(const int* __restrict__ deg,
                                                   float* __restrict__ dinv, int n) {
    int i = blockIdx.x * 256 + threadIdx.x;
    if (i < n) dinv[i] = rsqrtf((float)deg[i] + 1.0f);
}

// ---- 3-phase exclusive scan of deg -> off ----
__global__ __launch_bounds__(SCAN_T) void scan1(const int* __restrict__ deg,
                                                int* __restrict__ off,
                                                int* __restrict__ bsums, int n) {
    __shared__ int lds[SCAN_T];
    int base = blockIdx.x * SCAN_B + threadIdx.x * SCAN_E;
    int v[SCAN_E];
    int local = 0;
#pragma unroll
    for (int k = 0; k < SCAN_E; ++k) {
        v[k] = (base + k < n) ? deg[base + k] : 0;
        local += v[k];
    }
    lds[threadIdx.x] = local;
    __syncthreads();
    for (int o = 1; o < SCAN_T; o <<= 1) {
        int t = (threadIdx.x >= o) ? lds[threadIdx.x - o] : 0;
        __syncthreads();
        lds[threadIdx.x] += t;
        __syncthreads();
    }
    int prefix = lds[threadIdx.x] - local;
    if (threadIdx.x == SCAN_T - 1) bsums[blockIdx.x] = lds[threadIdx.x];
    int run = prefix;
#pragma unroll
    for (int k = 0; k < SCAN_E; ++k) {
        if (base + k < n) { off[base + k] = run; run += v[k]; }
    }
}

__global__ void scan2(int* bsums, int* off, int nb, int n) {
    if (threadIdx.x == 0 && blockIdx.x == 0) {
        int run = 0;
        for (int i = 0; i < nb; ++i) { int t = bsums[i]; bsums[i] = run; run += t; }
        off[n] = run;
    }
}

__global__ __launch_bounds__(SCAN_T) void scan3(int* __restrict__ off,
                                                int* __restrict__ cur,
                                                const int* __restrict__ bsums, int n) {
    int base = blockIdx.x * SCAN_B + threadIdx.x * SCAN_E;
    int add = bsums[blockIdx.x];
#pragma unroll
    for (int k = 0; k < SCAN_E; ++k) {
        int i = base + k;
        if (i < n) { int v = off[i] + add; off[i] = v; cur[i] = v; }
    }
}

// Scatter edges into CSR buckets by dst. Packed {src, weight_bits} single 8B store.
__global__ __launch_bounds__(256) void build_kernel(const void* ei, const int* flag,
                                                    const float* __restrict__ dinv,
                                                    int* __restrict__ cur,
                                                    int2* __restrict__ csr, int E) {
    int is64 = flag[0];
    long long e = (long long)blockIdx.x * 256 + threadIdx.x;
    if (e >= E) return;
    int s = load_edge(ei, e, is64);
    int d = load_edge(ei, (long long)E + e, is64);
    int pos = atomicAdd(&cur[d], 1);
    csr[pos] = make_int2(s, (int)__float_as_uint(dinv[s] * dinv[d]));
}

// ---- W prep: fp32 [K][Nc] -> transposed split-bf16 [N][KP], zero-padded ----
__global__ __launch_bounds__(256) void wprep(const float* __restrict__ W,
                                             short* __restrict__ Wh, short* __restrict__ Wl,
                                             int K, int KP, int Nc, int N) {
    int id = blockIdx.x * 256 + threadIdx.x;
    if (id >= N * KP) return;
    int nn = id / KP, k = id % KP;
    float v = (k < K && nn < Nc) ? W[(long long)k * Nc + nn] : 0.f;
    HL r = split_bf16(v);
    Wh[nn * KP + k] = r.h;
    Wl[nn * KP + k] = r.l;
}

// ---- MFMA GEMM: out[n x 64](bf16) = A[n x K](fp32) @ Wt^T, split-bf16 3-term ----
template<int KPAD>
__global__ __launch_bounds__(256) void gemm_mfma(const float* __restrict__ A,
                                                 const short* __restrict__ Wh,
                                                 const short* __restrict__ Wl,
                                                 unsigned short* __restrict__ out,
                                                 int n, int K) {
    __shared__ short Xh[128 * 32], Xl[128 * 32];
    __shared__ short Bh[64 * 32], Bl[64 * 32];
    const int t = threadIdx.x;
    const int row0 = blockIdx.x * 128;
    const int wid = t >> 6, lane = t & 63, q = lane >> 4, nn = lane & 15;

    f4v acc[2][4];
#pragma unroll
    for (int mt = 0; mt < 2; ++mt)
#pragma unroll
        for (int ct = 0; ct < 4; ++ct) acc[mt][ct] = (f4v){0.f, 0.f, 0.f, 0.f};

    for (int k0 = 0; k0 < KPAD; k0 += 32) {
        {
            int bn = t >> 2, kq = t & 3;
            *(s8v*)&Bh[bn * 32 + kq * 8] = *(const s8v*)&Wh[bn * KPAD + k0 + kq * 8];
            *(s8v*)&Bl[bn * 32 + kq * 8] = *(const s8v*)&Wl[bn * KPAD + k0 + kq * 8];
        }
        {
            int kq = t & 7, rbase = t >> 3;
#pragma unroll
            for (int rr = 0; rr < 4; ++rr) {
                int row = rr * 32 + rbase;
                int grow = row0 + row;
                int k = k0 + kq * 4;
                float v0 = 0.f, v1 = 0.f, v2 = 0.f, v3 = 0.f;
                if (grow < n) {
                    if (k + 4 <= K) {
                        float4 v = *(const float4*)&A[(long long)grow * K + k];
                        v0 = v.x; v1 = v.y; v2 = v.z; v3 = v.w;
                    } else {
                        if (k + 0 < K) v0 = A[(long long)grow * K + k + 0];
                        if (k + 1 < K) v1 = A[(long long)grow * K + k + 1];
                        if (k + 2 < K) v2 = A[(long long)grow * K + k + 2];
                        if (k + 3 < K) v3 = A[(long long)grow * K + k + 3];
                    }
                }
                HL r0 = split_bf16(v0), r1 = split_bf16(v1);
                HL r2 = split_bf16(v2), r3 = split_bf16(v3);
                s4v h4, l4;
                h4[0] = r0.h; l4[0] = r0.l;
                h4[1] = r1.h; l4[1] = r1.l;
                h4[2] = r2.h; l4[2] = r2.l;
                h4[3] = r3.h; l4[3] = r3.l;
                *(s4v*)&Xh[row * 32 + kq * 4] = h4;
                *(s4v*)&Xl[row * 32 + kq * 4] = l4;
            }
        }
        __syncthreads();

        const s8v ah0 = *(const s8v*)&Xh[(wid * 32 + nn) * 32 + q * 8];
        const s8v ah1 = *(const s8v*)&Xh[(wid * 32 + 16 + nn) * 32 + q * 8];
        const s8v al0 = *(const s8v*)&Xl[(wid * 32 + nn) * 32 + q * 8];
        const s8v al1 = *(const s8v*)&Xl[(wid * 32 + 16 + nn) * 32 + q * 8];
#pragma unroll
        for (int ct = 0; ct < 4; ++ct) {
            const s8v bh = *(const s8v*)&Bh[(ct * 16 + nn) * 32 + q * 8];
            const s8v bl = *(const s8v*)&Bl[(ct * 16 + nn) * 32 + q * 8];
            acc[0][ct] = __builtin_amdgcn_mfma_f32_16x16x32_bf16(ah0, bh, acc[0][ct], 0, 0, 0);
            acc[0][ct] = __builtin_amdgcn_mfma_f32_16x16x32_bf16(ah0, bl, acc[0][ct], 0, 0, 0);
            acc[0][ct] = __builtin_amdgcn_mfma_f32_16x16x32_bf16(al0, bh, acc[0][ct], 0, 0, 0);
            acc[1][ct] = __builtin_amdgcn_mfma_f32_16x16x32_bf16(ah1, bh, acc[1][ct], 0, 0, 0);
            acc[1][ct] = __builtin_amdgcn_mfma_f32_16x16x32_bf16(ah1, bl, acc[1][ct], 0, 0, 0);
            acc[1][ct] = __builtin_amdgcn_mfma_f32_16x16x32_bf16(al1, bh, acc[1][ct], 0, 0, 0);
        }
        __syncthreads();
    }

    // epilogue: C/D layout col=lane&15, row=(lane>>4)*4+r; store bf16
#pragma unroll
    for (int mt = 0; mt < 2; ++mt)
#pragma unroll
        for (int ct = 0; ct < 4; ++ct)
#pragma unroll
            for (int r = 0; r < 4; ++r) {
                int row = row0 + wid * 32 + mt * 16 + q * 4 + r;
                if (row < n) out[(long long)row * 64 + ct * 16 + nn] = rne_bf16(acc[mt][ct][r]);
            }
}

// Layer-1 gather: wave per node, lane = feature (64). Scalar CSR loads, unroll 4.
__global__ __launch_bounds__(256) void gather_l1(const int2* __restrict__ csr,
                                                 const int* __restrict__ off,
                                                 const unsigned short* __restrict__ h,
                                                 const float* __restrict__ dinv,
                                                 const float* __restrict__ b,
                                                 float* __restrict__ agg, int n) {
    const int lane = threadIdx.x & 63;
    const int node = __builtin_amdgcn_readfirstlane(blockIdx.x * 4 + (threadIdx.x >> 6));
    if (node >= n) return;
    int start = off[node], end = off[node + 1];
    float dv = dinv[node];
    float acc = dv * dv * bf16f(h[(long long)node * 64 + lane]);
    int j = start;
    for (; j + 4 <= end; j += 4) {
        int2 e0 = csr[j + 0], e1 = csr[j + 1], e2 = csr[j + 2], e3 = csr[j + 3];
        float f0 = bf16f(h[(long long)e0.x * 64 + lane]);
        float f1 = bf16f(h[(long long)e1.x * 64 + lane]);
        float f2 = bf16f(h[(long long)e2.x * 64 + lane]);
        float f3 = bf16f(h[(long long)e3.x * 64 + lane]);
        acc = fmaf(__uint_as_float((unsigned)e0.y), f0, acc);
        acc = fmaf(__uint_as_float((unsigned)e1.y), f1, acc);
        acc = fmaf(__uint_as_float((unsigned)e2.y), f2, acc);
        acc = fmaf(__uint_as_float((unsigned)e3.y), f3, acc);
    }
    for (; j < end; ++j) {
        int2 e = csr[j];
        acc = fmaf(__uint_as_float((unsigned)e.y), bf16f(h[(long long)e.x * 64 + lane]), acc);
    }
    float v = acc + b[lane];
    agg[(long long)node * 64 + lane] = v > 0.f ? v : 0.f;
}

// Layer-2 gather fused with bias, relu, log_softmax. h bf16 stride 64, cols 0..39.
__global__ __launch_bounds__(256) void gather_l2(const int2* __restrict__ csr,
                                                 const int* __restrict__ off,
                                                 const unsigned short* __restrict__ h,
                                                 const float* __restrict__ dinv,
                                                 const float* __restrict__ b,
                                                 float* __restrict__ out, int n) {
    const int lane = threadIdx.x & 63;
    const int node = __builtin_amdgcn_readfirstlane(blockIdx.x * 4 + (threadIdx.x >> 6));
    if (node >= n) return;
    int start = off[node], end = off[node + 1];
    float dv = dinv[node];
    const int act = (lane < NC) ? 1 : 0;
    float acc = act ? dv * dv * bf16f(h[(long long)node * 64 + lane]) : 0.f;
    int j = start;
    for (; j + 4 <= end; j += 4) {
        int2 e0 = csr[j + 0], e1 = csr[j + 1], e2 = csr[j + 2], e3 = csr[j + 3];
        if (act) {
            float f0 = bf16f(h[(long long)e0.x * 64 + lane]);
            float f1 = bf16f(h[(long long)e1.x * 64 + lane]);
            float f2 = bf16f(h[(long long)e2.x * 64 + lane]);
            float f3 = bf16f(h[(long long)e3.x * 64 + lane]);
            acc = fmaf(__uint_as_float((unsigned)e0.y), f0, acc);
            acc = fmaf(__uint_as_float((unsigned)e1.y), f1, acc);
            acc = fmaf(__uint_as_float((unsigned)e2.y), f2, acc);
            acc = fmaf(__uint_as_float((unsigned)e3.y), f3, acc);
        }
    }
    for (; j < end; ++j) {
        int2 e = csr[j];
        if (act) acc = fmaf(__uint_as_float((unsigned)e.y),
                            bf16f(h[(long long)e.x * 64 + lane]), acc);
    }
    float tv;
    if (act) {
        tv = acc + b[lane];
        tv = tv > 0.f ? tv : 0.f;
    } else {
        tv = -1e30f;
    }
    float m = tv;
#pragma unroll
    for (int o = 32; o > 0; o >>= 1) m = fmaxf(m, __shfl_xor(m, o));
    float ex = act ? expf(tv - m) : 0.f;
    float ssum = ex;
#pragma unroll
    for (int o = 32; o > 0; o >>= 1) ssum += __shfl_xor(ssum, o);
    if (act) out[(long long)node * NC + lane] = tv - m - logf(ssum);
}

static inline char* align256(char* p) {
    return (char*)(((uintptr_t)p + 255) & ~(uintptr_t)255);
}

extern "C" void kernel_launch(void* const* d_in, const int* in_sizes, int n_in,
                              void* d_out, int out_size, void* d_ws, size_t ws_size,
                              hipStream_t stream) {
    const float* x  = (const float*)d_in[0];
    const void*  ei = d_in[1];
    const float* W1 = (const float*)d_in[2];
    const float* b1 = (const float*)d_in[3];
    const float* W2 = (const float*)d_in[4];
    const float* b2 = (const float*)d_in[5];
    float* out = (float*)d_out;
    const int n = in_sizes[0] / NN_F;   // 100000
    const int E = in_sizes[1] / 2;      // 1600000
    const int nScanBlocks = (n + SCAN_B - 1) / SCAN_B;

    char* p = (char*)d_ws;
    int* flag = (int*)p;                 p = align256(p + 16 * sizeof(int));
    int* deg  = (int*)p;                 p = align256(p + (size_t)n * sizeof(int));
    int* off  = (int*)p;                 p = align256(p + (size_t)(n + 1) * sizeof(int));
    int* cur  = (int*)p;                 p = align256(p + (size_t)n * sizeof(int));
    int* bsums = (int*)p;                p = align256(p + 256 * sizeof(int));
    float* dinv = (float*)p;             p = align256(p + (size_t)n * sizeof(float));
    int2* csr = (int2*)p;                p = align256(p + (size_t)E * sizeof(int2));
    short* Wt1h = (short*)p;             p = align256(p + (size_t)64 * 512 * sizeof(short));
    short* Wt1l = (short*)p;             p = align256(p + (size_t)64 * 512 * sizeof(short));
    short* Wt2h = (short*)p;             p = align256(p + (size_t)64 * 64 * sizeof(short));
    short* Wt2l = (short*)p;             p = align256(p + (size_t)64 * 64 * sizeof(short));
    unsigned short* h1 = (unsigned short*)p; p = align256(p + (size_t)n * 64 * sizeof(unsigned short));
    float* agg1 = (float*)p;             p = align256(p + (size_t)n * 64 * sizeof(float));
    unsigned short* h2 = h1;  // reuse: h1 dead after gather_l1

    (void)hipMemsetAsync(deg, 0, (size_t)n * sizeof(int), stream);
    detect_kernel<<<1, 256, 0, stream>>>((const unsigned int*)ei, flag);
    deg_kernel<<<(E + 255) / 256, 256, 0, stream>>>(ei, flag, deg, E);
    dinv_kernel<<<(n + 255) / 256, 256, 0, stream>>>(deg, dinv, n);

    scan1<<<nScanBlocks, SCAN_T, 0, stream>>>(deg, off, bsums, n);
    scan2<<<1, 64, 0, stream>>>(bsums, off, nScanBlocks, n);
    scan3<<<nScanBlocks, SCAN_T, 0, stream>>>(off, cur, bsums, n);
    build_kernel<<<(E + 255) / 256, 256, 0, stream>>>(ei, flag, dinv, cur, csr, E);

    wprep<<<(64 * 512 + 255) / 256, 256, 0, stream>>>(W1, Wt1h, Wt1l, NN_F, 512, HID, 64);
    wprep<<<(64 * 64 + 255) / 256, 256, 0, stream>>>(W2, Wt2h, Wt2l, HID, 64, NC, 64);

    const int gBlocks = (n + 127) / 128;
    gemm_mfma<512><<<gBlocks, 256, 0, stream>>>(x, Wt1h, Wt1l, h1, n, NN_F);
    gather_l1<<<(n + 3) / 4, 256, 0, stream>>>(csr, off, h1, dinv, b1, agg1, n);

    gemm_mfma<64><<<gBlocks, 256, 0, stream>>>(agg1, Wt2h, Wt2l, h2, n, HID);
    gather_l2<<<(n + 3) / 4, 256, 0, stream>>>(csr, off, h2, dinv, b2, out, n);
}

// Round 6
// 593.317 us; speedup vs baseline: 5.5359x; 1.0241x over previous
//
#include <hip/hip_runtime.h>

#define NN_F 500
#define HID 64
#define NC 40
#define SCAN_T 256
#define SCAN_E 8
#define SCAN_B (SCAN_T * SCAN_E)

typedef short s8v __attribute__((ext_vector_type(8)));
typedef short s4v __attribute__((ext_vector_type(4)));
typedef float f4v __attribute__((ext_vector_type(4)));

__device__ __forceinline__ unsigned short rne_bf16(float x) {
    unsigned u = __float_as_uint(x);
    return (unsigned short)((u + 0x7fffu + ((u >> 16) & 1u)) >> 16);
}
__device__ __forceinline__ float bf16_lo(unsigned v) {   // low 16 bits as bf16
    return __uint_as_float(v << 16);
}
__device__ __forceinline__ float bf16_hi(unsigned v) {   // high 16 bits as bf16
    return __uint_as_float(v & 0xffff0000u);
}

// ---- edge_index may arrive as int32 (harness-converted) or raw int64. ----
__device__ __forceinline__ int load_edge(const void* ei, long long idx, int is64) {
    if (is64) return (int)((const long long*)ei)[idx];
    return ((const int*)ei)[idx];
}

__global__ __launch_bounds__(256) void detect_kernel(const unsigned int* w, int* flag) {
    __shared__ unsigned int red[256];
    unsigned int acc = 0;
    for (int i = threadIdx.x; i < 2048; i += 256) acc |= w[2 * i + 1];
    red[threadIdx.x] = acc;
    __syncthreads();
    for (int s = 128; s > 0; s >>= 1) {
        if (threadIdx.x < s) red[threadIdx.x] |= red[threadIdx.x + s];
        __syncthreads();
    }
    if (threadIdx.x == 0) flag[0] = (red[0] == 0u) ? 1 : 0;
}

__global__ __launch_bounds__(256) void deg_kernel(const void* ei, const int* flag,
                                                  int* deg, int E) {
    int is64 = flag[0];
    long long e = (long long)blockIdx.x * 256 + threadIdx.x;
    if (e < E) {
        int d = load_edge(ei, (long long)E + e, is64);
        atomicAdd(&deg[d], 1);
    }
}

__global__ __launch_bounds__(256) void dinv_kernel(const int* __restrict__ deg,
                                                   float* __restrict__ dinv, int n) {
    int i = blockIdx.x * 256 + threadIdx.x;
    if (i < n) dinv[i] = rsqrtf((float)deg[i] + 1.0f);
}

// ---- 3-phase exclusive scan of deg -> off ----
__global__ __launch_bounds__(SCAN_T) void scan1(const int* __restrict__ deg,
                                                int* __restrict__ off,
                                                int* __restrict__ bsums, int n) {
    __shared__ int lds[SCAN_T];
    int base = blockIdx.x * SCAN_B + threadIdx.x * SCAN_E;
    int v[SCAN_E];
    int local = 0;
#pragma unroll
    for (int k = 0; k < SCAN_E; ++k) {
        v[k] = (base + k < n) ? deg[base + k] : 0;
        local += v[k];
    }
    lds[threadIdx.x] = local;
    __syncthreads();
    for (int o = 1; o < SCAN_T; o <<= 1) {
        int t = (threadIdx.x >= o) ? lds[threadIdx.x - o] : 0;
        __syncthreads();
        lds[threadIdx.x] += t;
        __syncthreads();
    }
    int prefix = lds[threadIdx.x] - local;
    if (threadIdx.x == SCAN_T - 1) bsums[blockIdx.x] = lds[threadIdx.x];
    int run = prefix;
#pragma unroll
    for (int k = 0; k < SCAN_E; ++k) {
        if (base + k < n) { off[base + k] = run; run += v[k]; }
    }
}

__global__ void scan2(int* bsums, int* off, int nb, int n) {
    if (threadIdx.x == 0 && blockIdx.x == 0) {
        int run = 0;
        for (int i = 0; i < nb; ++i) { int t = bsums[i]; bsums[i] = run; run += t; }
        off[n] = run;
    }
}

__global__ __launch_bounds__(SCAN_T) void scan3(int* __restrict__ off,
                                                int* __restrict__ cur,
                                                const int* __restrict__ bsums, int n) {
    int base = blockIdx.x * SCAN_B + threadIdx.x * SCAN_E;
    int add = bsums[blockIdx.x];
#pragma unroll
    for (int k = 0; k < SCAN_E; ++k) {
        int i = base + k;
        if (i < n) { int v = off[i] + add; off[i] = v; cur[i] = v; }
    }
}

// Scatter edges into CSR buckets by dst. Packed {src, weight_bits} single 8B store.
__global__ __launch_bounds__(256) void build_kernel(const void* ei, const int* flag,
                                                    const float* __restrict__ dinv,
                                                    int* __restrict__ cur,
                                                    int2* __restrict__ csr, int E) {
    int is64 = flag[0];
    long long e = (long long)blockIdx.x * 256 + threadIdx.x;
    if (e >= E) return;
    int s = load_edge(ei, e, is64);
    int d = load_edge(ei, (long long)E + e, is64);
    int pos = atomicAdd(&cur[d], 1);
    csr[pos] = make_int2(s, (int)__float_as_uint(dinv[s] * dinv[d]));
}

// ---- W prep: fp32 [K][Nc] -> transposed bf16 [N][KP], zero-padded ----
__global__ __launch_bounds__(256) void wprep(const float* __restrict__ W,
                                             unsigned short* __restrict__ Wh,
                                             int K, int KP, int Nc, int N) {
    int id = blockIdx.x * 256 + threadIdx.x;
    if (id >= N * KP) return;
    int nn = id / KP, k = id % KP;
    float v = (k < K && nn < Nc) ? W[(long long)k * Nc + nn] : 0.f;
    Wh[nn * KP + k] = rne_bf16(v);
}

// ---- MFMA GEMM: out[n x 64](bf16) = A[n x K](fp32) @ Wt^T, pure bf16 ----
// Block tile: 128 rows x 64 cols, K-tile 32. 4 waves, each 32 rows x 64 cols.
template<int KPAD>
__global__ __launch_bounds__(256) void gemm_mfma(const float* __restrict__ A,
                                                 const unsigned short* __restrict__ Wh,
                                                 unsigned short* __restrict__ out,
                                                 int n, int K) {
    __shared__ unsigned short Xh[128 * 32];
    __shared__ unsigned short Bh[64 * 32];
    const int t = threadIdx.x;
    const int row0 = blockIdx.x * 128;
    const int wid = t >> 6, lane = t & 63, q = lane >> 4, nn = lane & 15;

    f4v acc[2][4];
#pragma unroll
    for (int mt = 0; mt < 2; ++mt)
#pragma unroll
        for (int ct = 0; ct < 4; ++ct) acc[mt][ct] = (f4v){0.f, 0.f, 0.f, 0.f};

    for (int k0 = 0; k0 < KPAD; k0 += 32) {
        {
            int bn = t >> 2, kq = t & 3;
            *(s8v*)&Bh[bn * 32 + kq * 8] = *(const s8v*)&Wh[bn * KPAD + k0 + kq * 8];
        }
        {
            int kq = t & 7, rbase = t >> 3;
#pragma unroll
            for (int rr = 0; rr < 4; ++rr) {
                int row = rr * 32 + rbase;
                int grow = row0 + row;
                int k = k0 + kq * 4;
                float v0 = 0.f, v1 = 0.f, v2 = 0.f, v3 = 0.f;
                if (grow < n) {
                    if (k + 4 <= K) {
                        float4 v = *(const float4*)&A[(long long)grow * K + k];
                        v0 = v.x; v1 = v.y; v2 = v.z; v3 = v.w;
                    } else {
                        if (k + 0 < K) v0 = A[(long long)grow * K + k + 0];
                        if (k + 1 < K) v1 = A[(long long)grow * K + k + 1];
                        if (k + 2 < K) v2 = A[(long long)grow * K + k + 2];
                        if (k + 3 < K) v3 = A[(long long)grow * K + k + 3];
                    }
                }
                s4v h4;
                h4[0] = (short)rne_bf16(v0);
                h4[1] = (short)rne_bf16(v1);
                h4[2] = (short)rne_bf16(v2);
                h4[3] = (short)rne_bf16(v3);
                *(s4v*)&Xh[row * 32 + kq * 4] = h4;
            }
        }
        __syncthreads();

        const s8v ah0 = *(const s8v*)&Xh[(wid * 32 + nn) * 32 + q * 8];
        const s8v ah1 = *(const s8v*)&Xh[(wid * 32 + 16 + nn) * 32 + q * 8];
#pragma unroll
        for (int ct = 0; ct < 4; ++ct) {
            const s8v bh = *(const s8v*)&Bh[(ct * 16 + nn) * 32 + q * 8];
            acc[0][ct] = __builtin_amdgcn_mfma_f32_16x16x32_bf16(ah0, bh, acc[0][ct], 0, 0, 0);
            acc[1][ct] = __builtin_amdgcn_mfma_f32_16x16x32_bf16(ah1, bh, acc[1][ct], 0, 0, 0);
        }
        __syncthreads();
    }

    // epilogue: C/D layout col=lane&15, row=(lane>>4)*4+r; store bf16
#pragma unroll
    for (int mt = 0; mt < 2; ++mt)
#pragma unroll
        for (int ct = 0; ct < 4; ++ct)
#pragma unroll
            for (int r = 0; r < 4; ++r) {
                int row = row0 + wid * 32 + mt * 16 + q * 4 + r;
                if (row < n) out[(long long)row * 64 + ct * 16 + nn] = rne_bf16(acc[mt][ct][r]);
            }
}

// Layer-1 gather: wave per node. lane = (edge slot g = lane>>4, feature quad fp = lane&15).
// Per iter: 4 edges, 8 B/lane row reads. Reduce across slots with shfl_xor(16/32).
__global__ __launch_bounds__(256) void gather_l1(const int2* __restrict__ csr,
                                                 const int* __restrict__ off,
                                                 const unsigned short* __restrict__ h,
                                                 const float* __restrict__ dinv,
                                                 const float* __restrict__ b,
                                                 float* __restrict__ agg, int n) {
    const int lane = threadIdx.x & 63;
    const int g = lane >> 4, fp = lane & 15;
    const int node = __builtin_amdgcn_readfirstlane(blockIdx.x * 4 + (threadIdx.x >> 6));
    if (node >= n) return;
    const int start = off[node], end = off[node + 1];
    f4v acc = (f4v){0.f, 0.f, 0.f, 0.f};
    int j = start;
    for (; j + 8 <= end; j += 8) {
        int2 ea = csr[j + g];
        int2 eb = csr[j + 4 + g];
        uint2 ha = *(const uint2*)(h + (long long)ea.x * 64 + fp * 4);
        uint2 hb = *(const uint2*)(h + (long long)eb.x * 64 + fp * 4);
        float wa = __uint_as_float((unsigned)ea.y);
        float wb = __uint_as_float((unsigned)eb.y);
        acc[0] = fmaf(wa, bf16_lo(ha.x), acc[0]);
        acc[1] = fmaf(wa, bf16_hi(ha.x), acc[1]);
        acc[2] = fmaf(wa, bf16_lo(ha.y), acc[2]);
        acc[3] = fmaf(wa, bf16_hi(ha.y), acc[3]);
        acc[0] = fmaf(wb, bf16_lo(hb.x), acc[0]);
        acc[1] = fmaf(wb, bf16_hi(hb.x), acc[1]);
        acc[2] = fmaf(wb, bf16_lo(hb.y), acc[2]);
        acc[3] = fmaf(wb, bf16_hi(hb.y), acc[3]);
    }
    for (; j < end; j += 4) {
        int jj = j + g;
        int2 e = csr[jj < end ? jj : end - 1];
        float w = (jj < end) ? __uint_as_float((unsigned)e.y) : 0.f;
        uint2 hv = *(const uint2*)(h + (long long)e.x * 64 + fp * 4);
        acc[0] = fmaf(w, bf16_lo(hv.x), acc[0]);
        acc[1] = fmaf(w, bf16_hi(hv.x), acc[1]);
        acc[2] = fmaf(w, bf16_lo(hv.y), acc[2]);
        acc[3] = fmaf(w, bf16_hi(hv.y), acc[3]);
    }
#pragma unroll
    for (int k = 0; k < 4; ++k) {
        acc[k] += __shfl_xor(acc[k], 16);
        acc[k] += __shfl_xor(acc[k], 32);
    }
    // self-loop + bias + relu
    float dv = dinv[node];
    uint2 hn = *(const uint2*)(h + (long long)node * 64 + fp * 4);
    acc[0] = fmaf(dv * dv, bf16_lo(hn.x), acc[0]);
    acc[1] = fmaf(dv * dv, bf16_hi(hn.x), acc[1]);
    acc[2] = fmaf(dv * dv, bf16_lo(hn.y), acc[2]);
    acc[3] = fmaf(dv * dv, bf16_hi(hn.y), acc[3]);
    float4 b4 = ((const float4*)b)[fp];
    if (g == 0) {
        float4 v;
        v.x = acc[0] + b4.x; v.x = v.x > 0.f ? v.x : 0.f;
        v.y = acc[1] + b4.y; v.y = v.y > 0.f ? v.y : 0.f;
        v.z = acc[2] + b4.z; v.z = v.z > 0.f ? v.z : 0.f;
        v.w = acc[3] + b4.w; v.w = v.w > 0.f ? v.w : 0.f;
        ((float4*)(agg + (long long)node * 64))[fp] = v;
    }
}

// Layer-2 gather fused with bias, relu, log_softmax. h bf16 stride 64, cols 0..39 valid
// (cols 40..63 are exactly 0 from zero-padded W2).
__global__ __launch_bounds__(256) void gather_l2(const int2* __restrict__ csr,
                                                 const int* __restrict__ off,
                                                 const unsigned short* __restrict__ h,
                                                 const float* __restrict__ dinv,
                                                 const float* __restrict__ b,
                                                 float* __restrict__ out, int n) {
    const int lane = threadIdx.x & 63;
    const int g = lane >> 4, fp = lane & 15;
    const int node = __builtin_amdgcn_readfirstlane(blockIdx.x * 4 + (threadIdx.x >> 6));
    if (node >= n) return;
    const int start = off[node], end = off[node + 1];
    f4v acc = (f4v){0.f, 0.f, 0.f, 0.f};
    int j = start;
    for (; j + 8 <= end; j += 8) {
        int2 ea = csr[j + g];
        int2 eb = csr[j + 4 + g];
        uint2 ha = *(const uint2*)(h + (long long)ea.x * 64 + fp * 4);
        uint2 hb = *(const uint2*)(h + (long long)eb.x * 64 + fp * 4);
        float wa = __uint_as_float((unsigned)ea.y);
        float wb = __uint_as_float((unsigned)eb.y);
        acc[0] = fmaf(wa, bf16_lo(ha.x), acc[0]);
        acc[1] = fmaf(wa, bf16_hi(ha.x), acc[1]);
        acc[2] = fmaf(wa, bf16_lo(ha.y), acc[2]);
        acc[3] = fmaf(wa, bf16_hi(ha.y), acc[3]);
        acc[0] = fmaf(wb, bf16_lo(hb.x), acc[0]);
        acc[1] = fmaf(wb, bf16_hi(hb.x), acc[1]);
        acc[2] = fmaf(wb, bf16_lo(hb.y), acc[2]);
        acc[3] = fmaf(wb, bf16_hi(hb.y), acc[3]);
    }
    for (; j < end; j += 4) {
        int jj = j + g;
        int2 e = csr[jj < end ? jj : end - 1];
        float w = (jj < end) ? __uint_as_float((unsigned)e.y) : 0.f;
        uint2 hv = *(const uint2*)(h + (long long)e.x * 64 + fp * 4);
        acc[0] = fmaf(w, bf16_lo(hv.x), acc[0]);
        acc[1] = fmaf(w, bf16_hi(hv.x), acc[1]);
        acc[2] = fmaf(w, bf16_lo(hv.y), acc[2]);
        acc[3] = fmaf(w, bf16_hi(hv.y), acc[3]);
    }
#pragma unroll
    for (int k = 0; k < 4; ++k) {
        acc[k] += __shfl_xor(acc[k], 16);
        acc[k] += __shfl_xor(acc[k], 32);
    }
    float dv = dinv[node];
    uint2 hn = *(const uint2*)(h + (long long)node * 64 + fp * 4);
    acc[0] = fmaf(dv * dv, bf16_lo(hn.x), acc[0]);
    acc[1] = fmaf(dv * dv, bf16_hi(hn.x), acc[1]);
    acc[2] = fmaf(dv * dv, bf16_lo(hn.y), acc[2]);
    acc[3] = fmaf(dv * dv, bf16_hi(hn.y), acc[3]);
    // bias + relu for features fp*4..fp*4+3 (valid iff fp < 10 since NC=40)
    float t0, t1, t2, t3;
    if (fp < 10) {
        float4 b4 = ((const float4*)b)[fp];
        t0 = acc[0] + b4.x; t0 = t0 > 0.f ? t0 : 0.f;
        t1 = acc[1] + b4.y; t1 = t1 > 0.f ? t1 : 0.f;
        t2 = acc[2] + b4.z; t2 = t2 > 0.f ? t2 : 0.f;
        t3 = acc[3] + b4.w; t3 = t3 > 0.f ? t3 : 0.f;
    } else {
        t0 = t1 = t2 = t3 = -1e30f;
    }
    float m = fmaxf(fmaxf(t0, t1), fmaxf(t2, t3));
#pragma unroll
    for (int o = 1; o < 16; o <<= 1) m = fmaxf(m, __shfl_xor(m, o));
    float ssum = 0.f;
    if (fp < 10) ssum = expf(t0 - m) + expf(t1 - m) + expf(t2 - m) + expf(t3 - m);
#pragma unroll
    for (int o = 1; o < 16; o <<= 1) ssum += __shfl_xor(ssum, o);
    if (g == 0 && fp < 10) {
        float ls = m + logf(ssum);
        float4 v = make_float4(t0 - ls, t1 - ls, t2 - ls, t3 - ls);
        ((float4*)(out + (long long)node * NC))[fp] = v;
    }
}

static inline char* align256(char* p) {
    return (char*)(((uintptr_t)p + 255) & ~(uintptr_t)255);
}

extern "C" void kernel_launch(void* const* d_in, const int* in_sizes, int n_in,
                              void* d_out, int out_size, void* d_ws, size_t ws_size,
                              hipStream_t stream) {
    const float* x  = (const float*)d_in[0];
    const void*  ei = d_in[1];
    const float* W1 = (const float*)d_in[2];
    const float* b1 = (const float*)d_in[3];
    const float* W2 = (const float*)d_in[4];
    const float* b2 = (const float*)d_in[5];
    float* out = (float*)d_out;
    const int n = in_sizes[0] / NN_F;   // 100000
    const int E = in_sizes[1] / 2;      // 1600000
    const int nScanBlocks = (n + SCAN_B - 1) / SCAN_B;

    char* p = (char*)d_ws;
    int* flag = (int*)p;                 p = align256(p + 16 * sizeof(int));
    int* deg  = (int*)p;                 p = align256(p + (size_t)n * sizeof(int));
    int* off  = (int*)p;                 p = align256(p + (size_t)(n + 1) * sizeof(int));
    int* cur  = (int*)p;                 p = align256(p + (size_t)n * sizeof(int));
    int* bsums = (int*)p;                p = align256(p + 256 * sizeof(int));
    float* dinv = (float*)p;             p = align256(p + (size_t)n * sizeof(float));
    int2* csr = (int2*)p;                p = align256(p + (size_t)E * sizeof(int2));
    unsigned short* Wt1 = (unsigned short*)p; p = align256(p + (size_t)64 * 512 * sizeof(short));
    unsigned short* Wt2 = (unsigned short*)p; p = align256(p + (size_t)64 * 64 * sizeof(short));
    unsigned short* h1 = (unsigned short*)p; p = align256(p + (size_t)n * 64 * sizeof(unsigned short));
    float* agg1 = (float*)p;             p = align256(p + (size_t)n * 64 * sizeof(float));
    unsigned short* h2 = h1;  // reuse: h1 dead after gather_l1

    (void)hipMemsetAsync(deg, 0, (size_t)n * sizeof(int), stream);
    detect_kernel<<<1, 256, 0, stream>>>((const unsigned int*)ei, flag);
    deg_kernel<<<(E + 255) / 256, 256, 0, stream>>>(ei, flag, deg, E);
    dinv_kernel<<<(n + 255) / 256, 256, 0, stream>>>(deg, dinv, n);

    scan1<<<nScanBlocks, SCAN_T, 0, stream>>>(deg, off, bsums, n);
    scan2<<<1, 64, 0, stream>>>(bsums, off, nScanBlocks, n);
    scan3<<<nScanBlocks, SCAN_T, 0, stream>>>(off, cur, bsums, n);
    build_kernel<<<(E + 255) / 256, 256, 0, stream>>>(ei, flag, dinv, cur, csr, E);

    wprep<<<(64 * 512 + 255) / 256, 256, 0, stream>>>(W1, Wt1, NN_F, 512, HID, 64);
    wprep<<<(64 * 64 + 255) / 256, 256, 0, stream>>>(W2, Wt2, HID, 64, NC, 64);

    const int gBlocks = (n + 127) / 128;
    gemm_mfma<512><<<gBlocks, 256, 0, stream>>>(x, Wt1, h1, n, NN_F);
    gather_l1<<<(n + 3) / 4, 256, 0, stream>>>(csr, off, h1, dinv, b1, agg1, n);

    gemm_mfma<64><<<gBlocks, 256, 0, stream>>>(agg1, Wt2, h2, n, HID);
    gather_l2<<<(n + 3) / 4, 256, 0, stream>>>(csr, off, h2, dinv, b2, out, n);
}